// Round 5
// baseline (916.349 us; speedup 1.0000x reference)
//
#include <hip/hip_runtime.h>
#include <hip/hip_bf16.h>

#define B_ 8
#define T_ 4096
#define C_ 512
#define S_ 64
#define KT 3
#define EPSC 1e-5f
#define PADB 5
#define RB 4128            // padded rows per batch: 5 + 4096 + 27

typedef __attribute__((ext_vector_type(8))) short bf16x8;
typedef __attribute__((ext_vector_type(8))) unsigned short u16x8;
typedef __attribute__((ext_vector_type(4))) float f32x4;
typedef __attribute__((address_space(3))) unsigned int lds_u32_t;
typedef const __attribute__((address_space(1))) unsigned int glb_u32_t;

#define VMWAIT(N) asm volatile("s_waitcnt vmcnt(" #N ")" ::: "memory")
#define CFENCE    asm volatile("" ::: "memory")

__device__ inline unsigned short f2bf(float x) {
    __hip_bfloat16 h = __float2bfloat16(x);
    return *reinterpret_cast<unsigned short*>(&h);
}
__device__ inline float bf2f(unsigned short u) {
    return __uint_as_float((unsigned)u << 16);
}

// ---- per-co sum of squares of v over (k, ci), atomically accumulated ----
__global__ void norm_partial(const float* __restrict__ v1, const float* __restrict__ v2,
                             float* __restrict__ normsq) {
    int j = blockIdx.y;
    int i = j >> 1;
    const float* v = ((j & 1) ? v2 : v1) + (size_t)i * KT * C_ * C_;
    int r0 = blockIdx.x * 16;
    int tid = threadIdx.x;
    float a0 = 0.f, a1 = 0.f;
    for (int r = 0; r < 16; ++r) {
        const float* row = v + (size_t)(r0 + r) * C_;
        float x = row[tid];
        float y = row[tid + 256];
        a0 += x * x; a1 += y * y;
    }
    atomicAdd(&normsq[j * C_ + tid], a0);
    atomicAdd(&normsq[j * C_ + tid + 256], a1);
}

// ---- wT[j][k][co][ci] = bf16(g[co] * v[k][ci][co] * rsqrt(normsq[j][co])) ----
__global__ void wt_kernel(const float* __restrict__ v1, const float* __restrict__ v2,
                          const float* __restrict__ g1, const float* __restrict__ g2,
                          const float* __restrict__ normsq, unsigned short* __restrict__ wT) {
    __shared__ float tile[64][65];
    int jk = blockIdx.y;
    int j = jk / 3, k = jk % 3;
    int i = j >> 1;
    const float* v = ((j & 1) ? v2 : v1) + ((size_t)i * KT + k) * C_ * C_;
    const float* g = ((j & 1) ? g2 : g1) + (size_t)i * C_;
    int tci = (blockIdx.x >> 3) * 64;
    int tco = (blockIdx.x & 7) * 64;
    int tid = threadIdx.x;
    int lr = tid >> 6, lc = tid & 63;
    for (int rr = 0; rr < 16; ++rr) {
        int ci = rr * 4 + lr;
        tile[ci][lc] = v[(size_t)(tci + ci) * C_ + tco + lc];
    }
    __syncthreads();
    for (int rr = 0; rr < 16; ++rr) {
        int co_l = rr * 4 + lr;
        int co = tco + co_l;
        float w = g[co] * rsqrtf(normsq[j * C_ + co]) * tile[lc][co_l];
        wT[((size_t)j * KT + k) * C_ * C_ + (size_t)co * C_ + tci + lc] = f2bf(w);
    }
}

// ---- zero the halo pad rows of padded z ----
__global__ void zero_pads(unsigned short* __restrict__ zp) {
    int q = blockIdx.x * 256 + threadIdx.x;
    int b = q >> 11, r = q & 2047;
    int row = r >> 6;
    int col = (r & 63) * 8;
    int prow = row < PADB ? row : row + T_;
    uint4 zz = make_uint4(0u, 0u, 0u, 0u);
    *(uint4*)(zp + ((size_t)b * RB + prow) * C_ + col) = zz;
}

// ---- partial sum / sumsq over T per (b, c) — only for the initial x ----
__global__ void stats_partial(const float* __restrict__ u, float* __restrict__ ssum,
                              float* __restrict__ ssq) {
    int c = blockIdx.y * 256 + threadIdx.x;
    int b = blockIdx.z;
    int t0 = blockIdx.x * 64;
    const float* p = u + ((size_t)b * T_ + t0) * C_ + c;
    float s1 = 0.f, s2 = 0.f;
    for (int t = 0; t < 64; ++t) {
        float x = p[(size_t)t * C_];
        s1 += x; s2 += x * x;
    }
    atomicAdd(&ssum[b * C_ + c], s1);
    atomicAdd(&ssq[b * C_ + c], s2);
}

// ---- finalize: mean/var + style GEMV -> per-(b,c) scale/shift ----
__global__ void adain_finalize(const float* __restrict__ ssum, const float* __restrict__ ssq,
                               const float* __restrict__ s, const float* __restrict__ fcw,
                               const float* __restrict__ fcb,
                               float* __restrict__ scale, float* __restrict__ shift) {
    int idx = blockIdx.x * 256 + threadIdx.x;
    int b = idx >> 9, c = idx & (C_ - 1);
    float mu = ssum[idx] * (1.f / T_);
    float var = ssq[idx] * (1.f / T_) - mu * mu;
    var = fmaxf(var, 0.f);
    float gamma = fcb[c], beta = fcb[C_ + c];
    const float* sp = s + b * S_;
    for (int p = 0; p < S_; ++p) {
        float sv = sp[p];
        gamma += sv * fcw[p * 2 * C_ + c];
        beta  += sv * fcw[p * 2 * C_ + C_ + c];
    }
    float sc = (1.f + gamma) * rsqrtf(var + EPSC);
    scale[idx] = sc;
    shift[idx] = beta - mu * sc;
}

// ---- z = bf16(snake(x*scale+shift, alpha)), fp32 input, into padded z ----
__global__ void act_kernel(const float* __restrict__ u, const float* __restrict__ scale,
                           const float* __restrict__ shift, const float* __restrict__ alpha,
                           unsigned short* __restrict__ zp) {
    size_t idx4 = (size_t)blockIdx.x * 256 + threadIdx.x;
    size_t e0 = idx4 * 4;
    int c = (int)(e0 & (C_ - 1));
    int b = (int)(e0 >> 21);
    const float4 xv = *(const float4*)(u + e0);
    const float4 scv = *(const float4*)(scale + b * C_ + c);
    const float4 shv = *(const float4*)(shift + b * C_ + c);
    const float4 av = *(const float4*)(alpha + c);
    float xx[4] = {xv.x, xv.y, xv.z, xv.w};
    float ss[4] = {scv.x, scv.y, scv.z, scv.w};
    float hh[4] = {shv.x, shv.y, shv.z, shv.w};
    float aa[4] = {av.x, av.y, av.z, av.w};
    ushort4 o;
    unsigned short r[4];
    #pragma unroll
    for (int q = 0; q < 4; ++q) {
        float val = xx[q] * ss[q] + hh[q];
        float sn = sinf(aa[q] * val);
        r[q] = f2bf(val + sn * sn / aa[q]);
    }
    o.x = r[0]; o.y = r[1]; o.z = r[2]; o.w = r[3];
    size_t dst = ((size_t)b * RB + PADB) * C_ + (e0 & (((size_t)1 << 21) - 1));
    *(ushort4*)(zp + dst) = o;
}

// ---- same, bf16 input (y1), 8 elems/thread ----
__global__ void act_kernel_bf16(const unsigned short* __restrict__ u,
                                const float* __restrict__ scale,
                                const float* __restrict__ shift,
                                const float* __restrict__ alpha,
                                unsigned short* __restrict__ zp) {
    size_t idx = (size_t)blockIdx.x * 256 + threadIdx.x;
    size_t e0 = idx * 8;
    int c = (int)(e0 & (C_ - 1));
    int b = (int)(e0 >> 21);
    u16x8 uv = *(const u16x8*)(u + e0);
    float scv[8], shv[8], av[8];
    *(float4*)scv = *(const float4*)(scale + b * C_ + c);
    *(float4*)(scv + 4) = *(const float4*)(scale + b * C_ + c + 4);
    *(float4*)shv = *(const float4*)(shift + b * C_ + c);
    *(float4*)(shv + 4) = *(const float4*)(shift + b * C_ + c + 4);
    *(float4*)av = *(const float4*)(alpha + c);
    *(float4*)(av + 4) = *(const float4*)(alpha + c + 4);
    u16x8 o;
    #pragma unroll
    for (int q = 0; q < 8; ++q) {
        float val = bf2f((unsigned short)uv[q]) * scv[q] + shv[q];
        float sn = sinf(av[q] * val);
        o[q] = f2bf(val + sn * sn / av[q]);
    }
    size_t dst = ((size_t)b * RB + PADB) * C_ + (e0 & (((size_t)1 << 21) - 1));
    *(u16x8*)(zp + dst) = o;
}

// ---- 3-tap dilated conv: 256x256 tile, 8 waves, dbuf + counted-vmcnt pipeline ----
#define BM 256
#define BN 256
#define AR 272    // staged A rows: t0-5 .. t0+266 in padded coords

__global__ __launch_bounds__(512, 2) void conv_kernel(
    const unsigned short* __restrict__ zp, const unsigned short* __restrict__ wTj,
    const float* __restrict__ bias, const float* __restrict__ residual,
    void* __restrict__ outv, int out_bf16,
    float* __restrict__ ssum, float* __restrict__ ssq, int dil) {
    __shared__ __align__(16) unsigned short As[2][AR * 64];   // 2 x 34816 B
    __shared__ __align__(16) unsigned short Bs[2][BN * 64];   // 2 x 32768 B
    int tid = threadIdx.x;
    int wv = tid >> 6, l = tid & 63;
    int l16 = l & 15, lg = l >> 4;
    int m0 = blockIdx.x * BM;
    int b = m0 >> 12, t0 = m0 & (T_ - 1);
    int n0 = blockIdx.y * BN;
    int wm = (wv >> 2) * 128, wn = (wv & 3) * 64;
    const unsigned short* aBase = zp + ((size_t)b * RB + t0) * C_;

    f32x4 acc[8][4];
    #pragma unroll
    for (int a = 0; a < 8; ++a)
        #pragma unroll
        for (int q = 0; q < 4; ++q) acc[a][q] = (f32x4){0.f, 0.f, 0.f, 0.f};

    // wave-uniform 5 gload_lds per call (4 full + 1 masked to lanes 0..15)
    auto STAGE_A = [&](int ci0, int pa) {
        int cbase = wv * 272;                    // 2176 chunks / 8 waves
        #pragma unroll
        for (int it = 0; it < 4; ++it) {
            int ch = cbase + it * 64 + l;
            int row = ch >> 3, c = ch & 7;
            const unsigned short* src = aBase + (size_t)row * C_ + ci0 + ((c ^ (row & 7)) * 8);
            __builtin_amdgcn_global_load_lds((glb_u32_t*)src,
                (lds_u32_t*)&As[pa][(cbase + it * 64) * 8], 16, 0, 0);
        }
        {
            int ch = cbase + 256 + (l & 15);
            int row = ch >> 3, c = ch & 7;
            const unsigned short* src = aBase + (size_t)row * C_ + ci0 + ((c ^ (row & 7)) * 8);
            if (l < 16)
                __builtin_amdgcn_global_load_lds((glb_u32_t*)src,
                    (lds_u32_t*)&As[pa][(cbase + 256) * 8], 16, 0, 0);
        }
    };
    // wave-uniform 4 gload_lds per call
    auto STAGE_B = [&](int ci0, int k, int pb) {
        #pragma unroll
        for (int it = 0; it < 4; ++it) {
            int chunk = it * 512 + tid;
            int row = chunk >> 3, c = chunk & 7;
            const unsigned short* src = wTj + ((size_t)k * C_ + n0 + row) * C_ + ci0 + ((c ^ (row & 7)) * 8);
            __builtin_amdgcn_global_load_lds((glb_u32_t*)src,
                (lds_u32_t*)&Bs[pb][(it * 512 + wv * 64) * 8], 16, 0, 0);
        }
    };

    STAGE_A(0, 0);       // 5 in flight
    STAGE_B(0, 0, 0);    // 9 in flight
    int pa = 0, pb = 0;

    for (int ci0 = 0; ci0 < C_; ci0 += 64) {
        #pragma unroll
        for (int k = 0; k < 3; ++k) {
            // issue next-buffer staging, then wait ONLY past it (counted vmcnt)
            if (k < 2) {
                STAGE_B(ci0, k + 1, pb ^ 1);
                VMWAIT(4);
            } else if (ci0 < C_ - 64) {
                STAGE_A(ci0 + 64, pa ^ 1);
                STAGE_B(ci0 + 64, 0, pb ^ 1);
                VMWAIT(9);
            } else {
                VMWAIT(0);
            }
            __builtin_amdgcn_s_barrier();   // all waves' current-buffer loads landed
            CFENCE;
            int sh = (k - 1) * dil + PADB;
            __builtin_amdgcn_s_setprio(1);
            #pragma unroll
            for (int ks = 0; ks < 2; ++ks) {
                bf16x8 afr[8], bfr[4];
                #pragma unroll
                for (int nf = 0; nf < 4; ++nf) {
                    int row = wn + nf * 16 + l16;
                    bfr[nf] = *(const bf16x8*)(&Bs[pb][row * 64 + (((ks * 4 + lg) ^ (row & 7)) * 8)]);
                }
                #pragma unroll
                for (int mf = 0; mf < 8; ++mf) {
                    int row = wm + mf * 16 + l16 + sh;
                    afr[mf] = *(const bf16x8*)(&As[pa][row * 64 + (((ks * 4 + lg) ^ (row & 7)) * 8)]);
                }
                #pragma unroll
                for (int mf = 0; mf < 8; ++mf)
                    #pragma unroll
                    for (int nf = 0; nf < 4; ++nf)
                        acc[mf][nf] = __builtin_amdgcn_mfma_f32_16x16x32_bf16(
                            afr[mf], bfr[nf], acc[mf][nf], 0, 0, 0);
            }
            __builtin_amdgcn_s_setprio(0);
            CFENCE;
            __builtin_amdgcn_s_barrier();   // all waves done reading; buffers may be reused
            pb ^= 1;
            if (k == 2) pa ^= 1;
        }
    }

    // epilogue: bias + optional residual, store (fp32 or bf16), fused IN stats
    #pragma unroll
    for (int nf = 0; nf < 4; ++nf) {
        int co = n0 + wn + nf * 16 + l16;
        float bv = bias[co];
        float s1 = 0.f, s2 = 0.f;
        #pragma unroll
        for (int mf = 0; mf < 8; ++mf) {
            #pragma unroll
            for (int r = 0; r < 4; ++r) {
                int t = t0 + wm + mf * 16 + lg * 4 + r;
                size_t idx = ((size_t)b * T_ + t) * C_ + co;
                float val = acc[mf][nf][r] + bv;
                if (residual) val += residual[idx];
                if (out_bf16) ((unsigned short*)outv)[idx] = f2bf(val);
                else          ((float*)outv)[idx] = val;
                s1 += val; s2 += val * val;
            }
        }
        s1 += __shfl_xor(s1, 16); s1 += __shfl_xor(s1, 32);
        s2 += __shfl_xor(s2, 16); s2 += __shfl_xor(s2, 32);
        if (lg == 0) {
            atomicAdd(&ssum[b * C_ + co], s1);
            atomicAdd(&ssq[b * C_ + co], s2);
        }
    }
}

extern "C" void kernel_launch(void* const* d_in, const int* in_sizes, int n_in,
                              void* d_out, int out_size, void* d_ws, size_t ws_size,
                              hipStream_t stream) {
    const float* x       = (const float*)d_in[0];
    const float* s       = (const float*)d_in[1];
    const float* fc1_w   = (const float*)d_in[2];
    const float* fc1_b   = (const float*)d_in[3];
    const float* alpha1  = (const float*)d_in[4];
    const float* conv1_v = (const float*)d_in[5];
    const float* conv1_g = (const float*)d_in[6];
    const float* conv1_b = (const float*)d_in[7];
    const float* fc2_w   = (const float*)d_in[8];
    const float* fc2_b   = (const float*)d_in[9];
    const float* alpha2  = (const float*)d_in[10];
    const float* conv2_v = (const float*)d_in[11];
    const float* conv2_g = (const float*)d_in[12];
    const float* conv2_b = (const float*)d_in[13];
    float* outp = (float*)d_out;

    char* ws = (char*)d_ws;
    const size_t MC = (size_t)B_ * T_ * C_;
    const size_t ZSZ = (size_t)B_ * RB * C_ * 2;
    unsigned short* z   = (unsigned short*)ws;
    unsigned short* y1b = (unsigned short*)(ws + ZSZ);              // bf16 mid tensor
    unsigned short* wT  = (unsigned short*)(ws + ZSZ + MC * 4);
    float* accum        = (float*)(ws + ZSZ + MC * 4 + (size_t)6 * KT * C_ * C_ * 2);
    float* normsq = accum;
    float* stats  = accum + 6 * C_;
    float* scale  = stats + 7 * 2 * B_ * C_;
    float* shift  = scale + B_ * C_;

    hipMemsetAsync(accum, 0, (size_t)(6 * C_ + 7 * 2 * B_ * C_) * sizeof(float), stream);
    zero_pads<<<64, 256, 0, stream>>>(z);
    norm_partial<<<dim3(96, 6), 256, 0, stream>>>(conv1_v, conv2_v, normsq);
    wt_kernel<<<dim3(64, 18), 256, 0, stream>>>(conv1_v, conv2_v, conv1_g, conv2_g, normsq, wT);

    const int dils[3] = {1, 3, 5};
    const float* xin = x;
    const int BC = B_ * C_;
    stats_partial<<<dim3(64, 2, 8), 256, 0, stream>>>(x, stats, stats + BC);

    for (int i = 0; i < 3; ++i) {
        float* p_in  = stats + (size_t)(2 * i) * 2 * BC;
        float* p_mid = stats + (size_t)(2 * i + 1) * 2 * BC;
        float* p_out = stats + (size_t)(2 * i + 2) * 2 * BC;

        adain_finalize<<<16, 256, 0, stream>>>(p_in, p_in + BC, s,
                                               fc1_w + (size_t)i * S_ * 2 * C_,
                                               fc1_b + (size_t)i * 2 * C_, scale, shift);
        act_kernel<<<16384, 256, 0, stream>>>(xin, scale, shift, alpha1 + (size_t)i * C_, z);
        conv_kernel<<<dim3(128, 2), 512, 0, stream>>>(
            z, wT + (size_t)(i * 2) * KT * C_ * C_, conv1_b + (size_t)i * C_,
            nullptr, y1b, 1, p_mid, p_mid + BC, dils[i]);

        adain_finalize<<<16, 256, 0, stream>>>(p_mid, p_mid + BC, s,
                                               fc2_w + (size_t)i * S_ * 2 * C_,
                                               fc2_b + (size_t)i * 2 * C_, scale, shift);
        act_kernel_bf16<<<8192, 256, 0, stream>>>(y1b, scale, shift, alpha2 + (size_t)i * C_, z);
        conv_kernel<<<dim3(128, 2), 512, 0, stream>>>(
            z, wT + (size_t)(i * 2 + 1) * KT * C_ * C_, conv2_b + (size_t)i * C_,
            xin, outp, 0, p_out, p_out + BC, 1);
        xin = outp;
    }
}

// Round 6
// 762.623 us; speedup vs baseline: 1.2016x; 1.2016x over previous
//
#include <hip/hip_runtime.h>
#include <hip/hip_bf16.h>

#define B_ 8
#define T_ 4096
#define C_ 512
#define S_ 64
#define KT 3
#define EPSC 1e-5f
#define PADB 5
#define RB 4128            // padded rows per batch: 5 + 4096 + 27

typedef __attribute__((ext_vector_type(8))) short bf16x8;
typedef __attribute__((ext_vector_type(4))) float f32x4;
typedef __attribute__((address_space(3))) unsigned int lds_u32_t;
typedef const __attribute__((address_space(1))) unsigned int glb_u32_t;

__device__ inline unsigned short f2bf(float x) {
    __hip_bfloat16 h = __float2bfloat16(x);
    return *reinterpret_cast<unsigned short*>(&h);
}

// ---- per-co sum of squares of v over (k, ci), atomically accumulated ----
__global__ void norm_partial(const float* __restrict__ v1, const float* __restrict__ v2,
                             float* __restrict__ normsq) {
    int j = blockIdx.y;
    int i = j >> 1;
    const float* v = ((j & 1) ? v2 : v1) + (size_t)i * KT * C_ * C_;
    int r0 = blockIdx.x * 16;
    int tid = threadIdx.x;
    float a0 = 0.f, a1 = 0.f;
    for (int r = 0; r < 16; ++r) {
        const float* row = v + (size_t)(r0 + r) * C_;
        float x = row[tid];
        float y = row[tid + 256];
        a0 += x * x; a1 += y * y;
    }
    atomicAdd(&normsq[j * C_ + tid], a0);
    atomicAdd(&normsq[j * C_ + tid + 256], a1);
}

// ---- wT[j][k][co][ci] = bf16(g[co] * v[k][ci][co] * rsqrt(normsq[j][co])) ----
__global__ void wt_kernel(const float* __restrict__ v1, const float* __restrict__ v2,
                          const float* __restrict__ g1, const float* __restrict__ g2,
                          const float* __restrict__ normsq, unsigned short* __restrict__ wT) {
    __shared__ float tile[64][65];
    int jk = blockIdx.y;
    int j = jk / 3, k = jk % 3;
    int i = j >> 1;
    const float* v = ((j & 1) ? v2 : v1) + ((size_t)i * KT + k) * C_ * C_;
    const float* g = ((j & 1) ? g2 : g1) + (size_t)i * C_;
    int tci = (blockIdx.x >> 3) * 64;
    int tco = (blockIdx.x & 7) * 64;
    int tid = threadIdx.x;
    int lr = tid >> 6, lc = tid & 63;
    for (int rr = 0; rr < 16; ++rr) {
        int ci = rr * 4 + lr;
        tile[ci][lc] = v[(size_t)(tci + ci) * C_ + tco + lc];
    }
    __syncthreads();
    for (int rr = 0; rr < 16; ++rr) {
        int co_l = rr * 4 + lr;
        int co = tco + co_l;
        float w = g[co] * rsqrtf(normsq[j * C_ + co]) * tile[lc][co_l];
        wT[((size_t)j * KT + k) * C_ * C_ + (size_t)co * C_ + tci + lc] = f2bf(w);
    }
}

// ---- zero the halo pad rows of padded z ----
__global__ void zero_pads(unsigned short* __restrict__ zp) {
    int q = blockIdx.x * 256 + threadIdx.x;
    int b = q >> 11, r = q & 2047;
    int row = r >> 6;
    int col = (r & 63) * 8;
    int prow = row < PADB ? row : row + T_;
    uint4 zz = make_uint4(0u, 0u, 0u, 0u);
    *(uint4*)(zp + ((size_t)b * RB + prow) * C_ + col) = zz;
}

// ---- partial sum / sumsq over T per (b, c) — only for the initial x ----
__global__ void stats_partial(const float* __restrict__ u, float* __restrict__ ssum,
                              float* __restrict__ ssq) {
    int c = blockIdx.y * 256 + threadIdx.x;
    int b = blockIdx.z;
    int t0 = blockIdx.x * 64;
    const float* p = u + ((size_t)b * T_ + t0) * C_ + c;
    float s1 = 0.f, s2 = 0.f;
    for (int t = 0; t < 64; ++t) {
        float x = p[(size_t)t * C_];
        s1 += x; s2 += x * x;
    }
    atomicAdd(&ssum[b * C_ + c], s1);
    atomicAdd(&ssq[b * C_ + c], s2);
}

// ---- finalize: mean/var + style GEMV -> per-(b,c) scale/shift ----
__global__ void adain_finalize(const float* __restrict__ ssum, const float* __restrict__ ssq,
                               const float* __restrict__ s, const float* __restrict__ fcw,
                               const float* __restrict__ fcb,
                               float* __restrict__ scale, float* __restrict__ shift) {
    int idx = blockIdx.x * 256 + threadIdx.x;
    int b = idx >> 9, c = idx & (C_ - 1);
    float mu = ssum[idx] * (1.f / T_);
    float var = ssq[idx] * (1.f / T_) - mu * mu;
    var = fmaxf(var, 0.f);
    float gamma = fcb[c], beta = fcb[C_ + c];
    const float* sp = s + b * S_;
    for (int p = 0; p < S_; ++p) {
        float sv = sp[p];
        gamma += sv * fcw[p * 2 * C_ + c];
        beta  += sv * fcw[p * 2 * C_ + C_ + c];
    }
    float sc = (1.f + gamma) * rsqrtf(var + EPSC);
    scale[idx] = sc;
    shift[idx] = beta - mu * sc;
}

// ---- z = bf16(snake(x*scale+shift, alpha)), fp32 input, into padded z ----
__global__ void act_kernel(const float* __restrict__ u, const float* __restrict__ scale,
                           const float* __restrict__ shift, const float* __restrict__ alpha,
                           unsigned short* __restrict__ zp) {
    size_t idx4 = (size_t)blockIdx.x * 256 + threadIdx.x;
    size_t e0 = idx4 * 4;
    int c = (int)(e0 & (C_ - 1));
    int b = (int)(e0 >> 21);
    const float4 xv = *(const float4*)(u + e0);
    const float4 scv = *(const float4*)(scale + b * C_ + c);
    const float4 shv = *(const float4*)(shift + b * C_ + c);
    const float4 av = *(const float4*)(alpha + c);
    float xx[4] = {xv.x, xv.y, xv.z, xv.w};
    float ss[4] = {scv.x, scv.y, scv.z, scv.w};
    float hh[4] = {shv.x, shv.y, shv.z, shv.w};
    float aa[4] = {av.x, av.y, av.z, av.w};
    ushort4 o;
    unsigned short r[4];
    #pragma unroll
    for (int q = 0; q < 4; ++q) {
        float val = xx[q] * ss[q] + hh[q];
        float sn = sinf(aa[q] * val);
        r[q] = f2bf(val + sn * sn / aa[q]);
    }
    o.x = r[0]; o.y = r[1]; o.z = r[2]; o.w = r[3];
    size_t dst = ((size_t)b * RB + PADB) * C_ + (e0 & (((size_t)1 << 21) - 1));
    *(ushort4*)(zp + dst) = o;
}

// ---- 3-tap dilated conv: 128x64 tile, 4 waves, 3 blocks/CU, single-buffered ----
#define BM 128
#define BN 64
#define AR 160    // staged A rows: t0-5 .. t0+154 in padded coords

__global__ __launch_bounds__(256, 3) void conv_kernel(
    const unsigned short* __restrict__ zp, const unsigned short* __restrict__ wTj,
    const float* __restrict__ bias, const float* __restrict__ residual,
    float* __restrict__ out,
    float* __restrict__ ssum, float* __restrict__ ssq, int dil) {
    __shared__ __align__(16) unsigned short As[AR * 64];       // 20480 B
    __shared__ __align__(16) unsigned short Bs[3 * BN * 64];   // 24576 B
    int tid = threadIdx.x;
    int wv = tid >> 6, l = tid & 63;
    int l16 = l & 15, lg = l >> 4;
    int m0 = blockIdx.x * BM;
    int b = m0 >> 12, t0 = m0 & (T_ - 1);
    int n0 = blockIdx.y * BN;
    int wm = (wv >> 1) * 64, wn = (wv & 1) * 32;
    const unsigned short* aBase = zp + ((size_t)b * RB + t0) * C_;

    f32x4 acc[4][2];
    #pragma unroll
    for (int a = 0; a < 4; ++a)
        #pragma unroll
        for (int q = 0; q < 2; ++q) acc[a][q] = (f32x4){0.f, 0.f, 0.f, 0.f};

    for (int ci0 = 0; ci0 < C_; ci0 += 64) {
        // A: 160 rows x 8 chunks = 1280 chunks, 5 wave-instrs/thread
        #pragma unroll
        for (int it = 0; it < 5; ++it) {
            int chunk = it * 256 + tid;
            int row = chunk >> 3, c = chunk & 7;
            const unsigned short* src = aBase + (size_t)row * C_ + ci0 + ((c ^ (row & 7)) * 8);
            __builtin_amdgcn_global_load_lds((glb_u32_t*)src,
                (lds_u32_t*)&As[(it * 256 + wv * 64) * 8], 16, 0, 0);
        }
        // B: 3 taps x 64 co x 8 chunks = 1536 chunks, 6 wave-instrs/thread
        #pragma unroll
        for (int it = 0; it < 6; ++it) {
            int chunk = it * 256 + tid;
            int row = chunk >> 3, c = chunk & 7;   // row 0..191: k=row>>6, co=row&63
            int k = row >> 6, co = (row & 63) + n0;
            const unsigned short* src = wTj + ((size_t)k * C_ + co) * C_ + ci0 + ((c ^ (row & 7)) * 8);
            __builtin_amdgcn_global_load_lds((glb_u32_t*)src,
                (lds_u32_t*)&Bs[(it * 256 + wv * 64) * 8], 16, 0, 0);
        }
        __syncthreads();

        #pragma unroll
        for (int k = 0; k < 3; ++k) {
            int sh = (k - 1) * dil + PADB;
            __builtin_amdgcn_s_setprio(1);
            #pragma unroll
            for (int ks = 0; ks < 2; ++ks) {
                bf16x8 afr[4], bfr[2];
                #pragma unroll
                for (int nf = 0; nf < 2; ++nf) {
                    int row = wn + nf * 16 + l16;           // 0..63
                    bfr[nf] = *(const bf16x8*)(&Bs[(k * BN + row) * 64 + (((ks * 4 + lg) ^ (row & 7)) * 8)]);
                }
                #pragma unroll
                for (int mf = 0; mf < 4; ++mf) {
                    int row = wm + mf * 16 + l16 + sh;      // <= 137 < 160
                    afr[mf] = *(const bf16x8*)(&As[row * 64 + (((ks * 4 + lg) ^ (row & 7)) * 8)]);
                }
                #pragma unroll
                for (int mf = 0; mf < 4; ++mf)
                    #pragma unroll
                    for (int nf = 0; nf < 2; ++nf)
                        acc[mf][nf] = __builtin_amdgcn_mfma_f32_16x16x32_bf16(
                            afr[mf], bfr[nf], acc[mf][nf], 0, 0, 0);
            }
            __builtin_amdgcn_s_setprio(0);
        }
        __syncthreads();
    }

    // epilogue: bias + optional residual, fp32 store (full 64B lines), fused IN stats
    #pragma unroll
    for (int nf = 0; nf < 2; ++nf) {
        int co = n0 + wn + nf * 16 + l16;
        float bv = bias[co];
        float s1 = 0.f, s2 = 0.f;
        #pragma unroll
        for (int mf = 0; mf < 4; ++mf) {
            #pragma unroll
            for (int r = 0; r < 4; ++r) {
                int t = t0 + wm + mf * 16 + lg * 4 + r;
                size_t idx = ((size_t)b * T_ + t) * C_ + co;
                float val = acc[mf][nf][r] + bv;
                if (residual) val += residual[idx];
                out[idx] = val;
                s1 += val; s2 += val * val;
            }
        }
        s1 += __shfl_xor(s1, 16); s1 += __shfl_xor(s1, 32);
        s2 += __shfl_xor(s2, 16); s2 += __shfl_xor(s2, 32);
        if (lg == 0) {
            atomicAdd(&ssum[b * C_ + co], s1);
            atomicAdd(&ssq[b * C_ + co], s2);
        }
    }
}

extern "C" void kernel_launch(void* const* d_in, const int* in_sizes, int n_in,
                              void* d_out, int out_size, void* d_ws, size_t ws_size,
                              hipStream_t stream) {
    const float* x       = (const float*)d_in[0];
    const float* s       = (const float*)d_in[1];
    const float* fc1_w   = (const float*)d_in[2];
    const float* fc1_b   = (const float*)d_in[3];
    const float* alpha1  = (const float*)d_in[4];
    const float* conv1_v = (const float*)d_in[5];
    const float* conv1_g = (const float*)d_in[6];
    const float* conv1_b = (const float*)d_in[7];
    const float* fc2_w   = (const float*)d_in[8];
    const float* fc2_b   = (const float*)d_in[9];
    const float* alpha2  = (const float*)d_in[10];
    const float* conv2_v = (const float*)d_in[11];
    const float* conv2_g = (const float*)d_in[12];
    const float* conv2_b = (const float*)d_in[13];
    float* outp = (float*)d_out;

    char* ws = (char*)d_ws;
    const size_t MC = (size_t)B_ * T_ * C_;
    const size_t ZSZ = (size_t)B_ * RB * C_ * 2;
    unsigned short* z  = (unsigned short*)ws;
    float* y1          = (float*)(ws + ZSZ);
    unsigned short* wT = (unsigned short*)(ws + ZSZ + MC * 4);
    float* accum       = (float*)(ws + ZSZ + MC * 4 + (size_t)6 * KT * C_ * C_ * 2);
    float* normsq = accum;
    float* stats  = accum + 6 * C_;
    float* scale  = stats + 7 * 2 * B_ * C_;
    float* shift  = scale + B_ * C_;

    hipMemsetAsync(accum, 0, (size_t)(6 * C_ + 7 * 2 * B_ * C_) * sizeof(float), stream);
    zero_pads<<<64, 256, 0, stream>>>(z);
    norm_partial<<<dim3(96, 6), 256, 0, stream>>>(conv1_v, conv2_v, normsq);
    wt_kernel<<<dim3(64, 18), 256, 0, stream>>>(conv1_v, conv2_v, conv1_g, conv2_g, normsq, wT);

    const int dils[3] = {1, 3, 5};
    const float* xin = x;
    const int BC = B_ * C_;
    stats_partial<<<dim3(64, 2, 8), 256, 0, stream>>>(x, stats, stats + BC);

    for (int i = 0; i < 3; ++i) {
        float* p_in  = stats + (size_t)(2 * i) * 2 * BC;
        float* p_mid = stats + (size_t)(2 * i + 1) * 2 * BC;
        float* p_out = stats + (size_t)(2 * i + 2) * 2 * BC;

        adain_finalize<<<16, 256, 0, stream>>>(p_in, p_in + BC, s,
                                               fc1_w + (size_t)i * S_ * 2 * C_,
                                               fc1_b + (size_t)i * 2 * C_, scale, shift);
        act_kernel<<<16384, 256, 0, stream>>>(xin, scale, shift, alpha1 + (size_t)i * C_, z);
        conv_kernel<<<dim3(256, 8), 256, 0, stream>>>(
            z, wT + (size_t)(i * 2) * KT * C_ * C_, conv1_b + (size_t)i * C_,
            nullptr, y1, p_mid, p_mid + BC, dils[i]);

        adain_finalize<<<16, 256, 0, stream>>>(p_mid, p_mid + BC, s,
                                               fc2_w + (size_t)i * S_ * 2 * C_,
                                               fc2_b + (size_t)i * 2 * C_, scale, shift);
        act_kernel<<<16384, 256, 0, stream>>>(y1, scale, shift, alpha2 + (size_t)i * C_, z);
        conv_kernel<<<dim3(256, 8), 256, 0, stream>>>(
            z, wT + (size_t)(i * 2 + 1) * KT * C_ * C_, conv2_b + (size_t)i * C_,
            xin, outp, p_out, p_out + BC, 1);
        xin = outp;
    }
}